// Round 7
// baseline (78.682 us; speedup 1.0000x reference)
//
#include <hip/hip_runtime.h>

// out[b,h,t,f] = sum_{r=0..64} a[b,h,t,r] * v[b,h, t+r-32, f]  (zero-padded in t)
// B=8 H=16 T=4096 F=64 R=65, fp32 in/out. bf16 MFMA (absmax 0.25 vs thr 1.0).
//
// Round 7: ring-buffered v. The per-block tile walk advances 64 rows but each
// window is 128 rows -> round-6 re-loaded half of v every tile. sv is now a
// time-ring (128 slots, reads 8-aligned so b128 never wraps): steady-state
// tiles load only the NEW 64 rows (16 loads/thread, was 32). Frees 16 VGPRs ->
// launch_bounds(256,5) + NTPB=4 (grid 2048) for 5 blocks/CU (LDS 29.7KB x5 fits).
// Pipeline per tile: SCATTER(i) [a band + v ring seg]; bar; ISSUE(i+1);
// COMPUTE+STORE(i); bar.

#define TT 4096
#define RRR 65
#define FF 64
#define TILE 64
#define SA_S 100     // bf16 row stride
#define SV_S 132     // bf16 row stride; ring occupies c in [0,128)
#define NTPB 4       // tiles per block -> 16 blocks per (b,h), grid 2048
#define RM 127       // ring mask

typedef short bf16x8 __attribute__((ext_vector_type(8)));
typedef float f32x16 __attribute__((ext_vector_type(16)));

__device__ __forceinline__ unsigned short f2bf(float x) {
    unsigned int u = __float_as_uint(x);
    u += 0x7fff + ((u >> 16) & 1);            // RNE
    return (unsigned short)(u >> 16);
}
__device__ __forceinline__ unsigned pk2(float lo, float hi) {
    return (unsigned)f2bf(lo) | ((unsigned)f2bf(hi) << 16);
}

__global__ __launch_bounds__(256, 5)
void unfold_mfma(const float* __restrict__ a, const float* __restrict__ v,
                 float* __restrict__ out) {
    __shared__ __align__(16) unsigned short sa[TILE * SA_S];  // 12800 B
    __shared__ __align__(16) unsigned short sv[FF * SV_S];    // 16896 B

    const int tid = threadIdx.x;
    const int f   = tid & 63;
    const int wv  = tid >> 6;

    const int bh = blockIdx.x >> 4;                 // 16 blocks per (b,h)
    const int T0 = (blockIdx.x & 15) << 8;          // 256-row span per block

    const float* vsl = v + (size_t)bh * TT * FF;
    const size_t obase = (size_t)bh * TT * FF;

    // ---- one-time zero-prefill of sa (band complement stays 0 across tiles) ----
    {
        uint4 z = make_uint4(0, 0, 0, 0);
        uint4* sp = (uint4*)sa;
        #pragma unroll
        for (int it = 0; it < 4; ++it) {
            int lin = tid + it * 256;
            if (lin < (TILE * SA_S) / 8) sp[lin] = z;
        }
    }

    float4 aq[4];
    float  ae[2];
    float  vv[4][4];

    int t0 = T0;
    const float* arow = a + ((size_t)bh * TT + t0) * RRR;

#define ISSUE_A() do {                                                         \
    _Pragma("unroll")                                                          \
    for (int it = 0; it < 4; ++it) {                                           \
        int lin = tid + it * 256;                                              \
        if (lin < TILE * 15) {                                                 \
            int R = lin / 15, j = lin - R * 15;                                \
            int r0 = (4 - (R & 3)) & 3;                                        \
            aq[it] = *(const float4*)(arow + (size_t)R * RRR + r0 + 4 * j);    \
        }                                                                      \
    }                                                                          \
    _Pragma("unroll")                                                          \
    for (int it = 0; it < 2; ++it) {                                           \
        int lin = tid + it * 256;                                              \
        if (lin < TILE * 5) {                                                  \
            int R = lin / 5, e = lin - R * 5;                                  \
            int r0 = (4 - (R & 3)) & 3;                                        \
            int r = (e < r0) ? e : 60 + e;                                     \
            ae[it] = arow[(size_t)R * RRR + r];                                \
        }                                                                      \
    }                                                                          \
} while (0)

    // load 64 new rows [s0, s0+64); wave wv handles rows [s0+16wv, +16)
#define ISSUE_V(s0) do {                                                       \
    const int gb = (s0) + 16 * wv;                                             \
    if ((s0) + 64 <= TT) {                                                     \
        _Pragma("unroll")                                                      \
        for (int it = 0; it < 4; ++it)                                         \
            _Pragma("unroll")                                                  \
            for (int j = 0; j < 4; ++j)                                        \
                vv[it][j] = vsl[(size_t)(gb + 4 * it + j) * FF + f];           \
    } else {                                                                   \
        _Pragma("unroll")                                                      \
        for (int it = 0; it < 4; ++it)                                         \
            _Pragma("unroll")                                                  \
            for (int j = 0; j < 4; ++j) {                                      \
                int g = gb + 4 * it + j;                                       \
                vv[it][j] = (g < TT) ? vsl[(size_t)g * FF + f] : 0.f;          \
            }                                                                  \
    }                                                                          \
} while (0)

#define SCAT_A() do {                                                          \
    _Pragma("unroll")                                                          \
    for (int it = 0; it < 4; ++it) {                                           \
        int lin = tid + it * 256;                                              \
        if (lin < TILE * 15) {                                                 \
            int R = lin / 15, j = lin - R * 15;                                \
            int r0 = (4 - (R & 3)) & 3;                                        \
            int rq = r0 + 4 * j;                                               \
            float4 q = aq[it];                                                 \
            uint2 pw; pw.x = pk2(q.x, q.y); pw.y = pk2(q.z, q.w);              \
            *(uint2*)&sa[R * SA_S + (R & 31) + rq] = pw;                       \
        }                                                                      \
    }                                                                          \
    _Pragma("unroll")                                                          \
    for (int it = 0; it < 2; ++it) {                                           \
        int lin = tid + it * 256;                                              \
        if (lin < TILE * 5) {                                                  \
            int R = lin / 5, e = lin - R * 5;                                  \
            int r0 = (4 - (R & 3)) & 3;                                        \
            int r = (e < r0) ? e : 60 + e;                                     \
            sa[R * SA_S + (R & 31) + r] = f2bf(ae[it]);                        \
        }                                                                      \
    }                                                                          \
} while (0)

    // write the staged 64-row segment into ring slots ((s0)+16wv+4it)&RM
#define SCAT_V(s0) do {                                                        \
    const int cb = (s0) + 16 * wv;                                             \
    _Pragma("unroll")                                                          \
    for (int it = 0; it < 4; ++it) {                                           \
        uint2 pw; pw.x = pk2(vv[it][0], vv[it][1]);                            \
        pw.y = pk2(vv[it][2], vv[it][3]);                                      \
        *(uint2*)&sv[f * SV_S + ((cb + 4 * it) & RM)] = pw;                    \
    }                                                                          \
} while (0)

    // ---- prologue: a(tile0) + full 128-row v window [T0-32, T0+96) ----
    ISSUE_A();
    {
        float pv[8][4];
        const int gb = T0 - 32 + 32 * wv;
        if (T0 >= 32) {
            #pragma unroll
            for (int it = 0; it < 8; ++it)
                #pragma unroll
                for (int j = 0; j < 4; ++j)
                    pv[it][j] = vsl[(size_t)(gb + 4 * it + j) * FF + f];
        } else {
            #pragma unroll
            for (int it = 0; it < 8; ++it)
                #pragma unroll
                for (int j = 0; j < 4; ++j) {
                    int g = gb + 4 * it + j;
                    pv[it][j] = (g >= 0) ? vsl[(size_t)g * FF + f] : 0.f;
                }
        }
        #pragma unroll
        for (int it = 0; it < 8; ++it) {
            uint2 pw; pw.x = pk2(pv[it][0], pv[it][1]);
            pw.y = pk2(pv[it][2], pv[it][3]);
            *(uint2*)&sv[f * SV_S + ((gb + 4 * it) & RM)] = pw;
        }
    }
    __syncthreads();   // sa prefill + sv window visible

    const int n  = f & 31;
    const int hi = f >> 5;
    const int wr = wv >> 1;
    const int wc = wv & 1;
    const int Rw = 32 * wr + n;

    #pragma unroll 1
    for (int i = 0; i < NTPB; ++i) {
        SCAT_A();
        if (i > 0) SCAT_V(t0 + 32);      // staged segment = [t0+32, t0+96)
        const int cur_t0 = t0;
        __syncthreads();

        if (i + 1 < NTPB) {
            t0 += TILE;
            arow = a + ((size_t)bh * TT + t0) * RRR;
            ISSUE_A();                    // a for next tile
            ISSUE_V(cur_t0 + 96);         // next tile's new 64 v rows
        }

        // ---- MFMA: wave (wr,wc) -> rows [cur_t0+32wr,+32), cols [32wc,+32) ----
        const int cbase = (cur_t0 - 32) & RM;    // ring origin of this window
        f32x16 acc = {};
        #pragma unroll
        for (int kb = 0; kb < 6; ++kb) {
            const int cp = kb * 16 + hi * 8;
            bf16x8 af = *(const bf16x8*)&sa[Rw * SA_S + cp];
            bf16x8 bv = *(const bf16x8*)&sv[(32 * wc + n) * SV_S
                                            + ((cbase + 32 * wr + cp) & RM)];
            acc = __builtin_amdgcn_mfma_f32_32x32x16_bf16(af, bv, acc, 0, 0, 0);
        }

        // C/D: col = lane&31, row = (reg&3) + 8*(reg>>2) + 4*(lane>>5)
        float* op = out + obase + (size_t)(cur_t0 + 32 * wr) * FF + 32 * wc;
        #pragma unroll
        for (int reg = 0; reg < 16; ++reg) {
            int row = (reg & 3) + 8 * (reg >> 2) + 4 * hi;
            __builtin_nontemporal_store(acc[reg], &op[row * FF + n]);
        }
        __syncthreads();             // ring/sa free for next scatter
    }
}

extern "C" void kernel_launch(void* const* d_in, const int* in_sizes, int n_in,
                              void* d_out, int out_size, void* d_ws, size_t ws_size,
                              hipStream_t stream) {
    const float* a = (const float*)d_in[0];
    const float* v = (const float*)d_in[1];
    float* out = (float*)d_out;

    const int BH = in_sizes[1] / (TT * FF);          // 128
    const int grid = BH * (TT / TILE) / NTPB;        // 2048 blocks

    unfold_mfma<<<grid, 256, 0, stream>>>(a, v, out);
}